// Round 6
// baseline (2939.780 us; speedup 1.0000x reference)
//
#include <hip/hip_runtime.h>
#include <math.h>
#include <stdint.h>

// Problem constants
#define NQ 8
#define DIMV 256
#define KCODES 1024
#define NTOK 65536              // 32*2048
#define NELEM (NTOK * DIMV)     // 16777216
#define TOKPB 32                // tokens per block in fused kernel

typedef _Float16 f16x8 __attribute__((ext_vector_type(8)));
typedef float    f32x16 __attribute__((ext_vector_type(16)));

// rotate-left-3 of a 5-bit slot index (bijective bank-spreading permutation)
__device__ __forceinline__ int rotl3(int s) { return ((s << 3) | (s >> 2)) & 31; }

// ---------------------------------------------------------------------------
// Pre-pass 1: transpose embeds [q][d][k] -> embedT [q][k][d] (fp32, for the
// quantize gather in the update phase).
// ---------------------------------------------------------------------------
__global__ __launch_bounds__(256)
void vq_transpose(const float* __restrict__ embeds, float* __restrict__ embedT) {
    const int idx = blockIdx.x * 256 + threadIdx.x;       // 0 .. 2097151
    const int q   = idx >> 18;
    const int rem = idx & 262143;
    const int k   = rem >> 8;
    const int d   = rem & 255;
    embedT[idx] = embeds[q * 262144 + d * 1024 + k];
}

// Pre-pass 2: e2[q][k] = sum_d embed[q][d][k]^2 (fp32)
__global__ __launch_bounds__(256)
void vq_e2(const float* __restrict__ embeds, float* __restrict__ e2) {
    const int idx = blockIdx.x * 256 + threadIdx.x;       // 0 .. 8191
    const int q = idx >> 10;
    const int k = idx & 1023;
    const float* e = embeds + q * 262144 + k;
    float s = 0.f;
    for (int d = 0; d < DIMV; ++d) {
        const float v = e[d * 1024];
        s += v * v;
    }
    e2[idx] = s;
}

// ---------------------------------------------------------------------------
// Pre-pass 3: split embed into fp16 hi/lo laid out as per-(layer,chunk,range)
// 4 KB images read straight into registers by the fused kernel:
//   embedB[q][chunk(16)][w(16)][part(2)][s(128)][j(8)]   (halfs)
// s = h*64 + cl ; d = chunk*16 + h*8 + j ; k = w*64 + cl
// Fragment read: lane(l32,h32), sub-tile ct -> s = h32*64 + ct*32 + l32
// (lane-contiguous 16B slots -> one coalesced global_load_dwordx4).
// ---------------------------------------------------------------------------
__global__ __launch_bounds__(256)
void vq_embedB(const float* __restrict__ embeds, _Float16* __restrict__ embedB) {
    const int idx = blockIdx.x * 256 + threadIdx.x;       // 0 .. 4194303
    const int j    = idx & 7;
    const int s    = (idx >> 3) & 127;
    const int part = (idx >> 10) & 1;
    const int w    = (idx >> 11) & 15;
    const int c    = (idx >> 15) & 15;
    const int q    = idx >> 19;
    const int h  = s >> 6;
    const int cl = s & 63;
    const int d  = c * 16 + h * 8 + j;
    const int k  = w * 64 + cl;
    const float v = embeds[q * 262144 + d * 1024 + k];
    const _Float16 hi = (_Float16)v;
    embedB[idx] = (part == 0) ? hi : (_Float16)(v - (float)hi);
}

// ---------------------------------------------------------------------------
// Fused 8-layer VQ kernel (round-5 restructure): 2048 blocks x 512 threads
// (8 waves), 32 tokens/block. Residual lives in LDS (fp16 hi/lo) across all
// 8 layers. Each wave owns 128 codes, processed as FOUR sequential 32-code
// passes; with a single 32-token tile the pass accumulator is ONE f32x16
// (16 regs), so hot-loop register demand (~65) sits far below the 128-reg
// cap -> zero spill, and the 39 KB LDS footprint lets 2-4 blocks co-reside
// per CU. Independent 8-wave barrier domains overlap one block's MFMA
// K-loop with another block's argmin/gather/loss phases (the round-4
// profile showed 47% occupancy and every pipe idle: stall-bound).
// ---------------------------------------------------------------------------
// LDS layout (bytes):
//  [0,     16384)  A_hi : 32 rows x 256 d fp16; 16B-block s of row t at
//                         slot rotl3(s)^(t&31)
//  [16384, 32768)  A_lo : same layout
//  [32768, 33888)  bestS  float[8][35]  (stride 35: bank-spread)
//  [33888, 35008)  bestI  int  [8][35]
//  [35008, 35136)  indF   int  [32]
//  [35136, 35168)  lossRed float[8]
//  [35200, 39296)  e2Lds  float[1024]
#define LDS_BYTES 39296

__global__ __launch_bounds__(512, 4)
void vq_fused(const float* __restrict__ x, float* __restrict__ out,
              const float* __restrict__ embedT, const float* __restrict__ e2,
              const _Float16* __restrict__ embedB,
              float* __restrict__ lossSum, int* __restrict__ counts) {
    extern __shared__ char smem[];
    _Float16* Ahi = (_Float16*)smem;
    _Float16* Alo = (_Float16*)(smem + 16384);
    float* bestS   = (float*)(smem + 32768);
    int*   bestI   = (int*)(smem + 33888);
    int*   indF    = (int*)(smem + 35008);
    float* lossRed = (float*)(smem + 35136);
    float* e2Lds   = (float*)(smem + 35200);

    const int tid    = threadIdx.x;
    const int wave   = tid >> 6;       // 0..7
    const int lane   = tid & 63;
    const int l32    = lane & 31;
    const int h32    = lane >> 5;
    const int tok0   = blockIdx.x * TOKPB;

    // ---- stage x -> A hi/lo (swizzled), ONCE for all 8 layers ----
#pragma unroll
    for (int k = 0; k < 2; ++k) {
        const int si = tid + k * 512;          // 0..1023 (t,s) pairs
        const int t  = si >> 5;
        const int s  = si & 31;
        const float4 v0 = *(const float4*)(x + (tok0 + t) * 256 + s * 8);
        const float4 v1 = *(const float4*)(x + (tok0 + t) * 256 + s * 8 + 4);
        const float vv[8] = {v0.x, v0.y, v0.z, v0.w, v1.x, v1.y, v1.z, v1.w};
        f16x8 h8, l8;
#pragma unroll
        for (int e = 0; e < 8; ++e) {
            const _Float16 hi = (_Float16)vv[e];
            h8[e] = hi;
            l8[e] = (_Float16)(vv[e] - (float)hi);
        }
        const int ss = rotl3(s) ^ (t & 31);
        ((f16x8*)(Ahi + t * 256))[ss] = h8;
        ((f16x8*)(Alo + t * 256))[ss] = l8;
    }

    // ---- 8 residual-VQ layers, residual resident in LDS ----
#pragma unroll 1
    for (int q = 0; q < NQ; ++q) {
        const _Float16* embedBq = embedB + q * 524288;
        const float*    embedTq = embedT + q * (KCODES * DIMV);

        // stage this layer's e2 into LDS (broadcast-read in score phase)
        e2Lds[tid]       = e2[q * KCODES + tid];
        e2Lds[tid + 512] = e2[q * KCODES + tid + 512];
        // barrier covers: initial/updated A writes + e2 writes
        __syncthreads();

        // running per-token best over this wave's 128 codes
        float bsv = 3.4e38f;
        int   biv = 0x7fffffff;

        // ---- four 32-code passes: acc = 16 regs, depth-2 B prefetch ----
#pragma unroll
        for (int p = 0; p < 4; ++p) {
            f32x16 acc;
#pragma unroll
            for (int r = 0; r < 16; ++r) acc[r] = 0.f;

            // 4 KB image (2*wave + p>>1) covers codes [wave*128+(p>>1)*64, +64);
            // (p&1) selects the 32-code half (ct offset 512 B).
            const char* gBp = (const char*)embedBq + (2 * wave + (p >> 1)) * 4096
                              + (p & 1) * 512 + h32 * 1024 + l32 * 16;

            // 3-slot rotating prefetch buffer (all indices compile-time)
            f16x8 bH[3], bL[3];
            bH[0] = *(const f16x8*)(gBp);
            bL[0] = *(const f16x8*)(gBp + 2048);
            bH[1] = *(const f16x8*)(gBp + 65536);
            bL[1] = *(const f16x8*)(gBp + 65536 + 2048);

#pragma unroll
            for (int c = 0; c < 16; ++c) {
                const int cs = c % 3;
                if (c < 14) {
                    const char* gBn = gBp + (c + 2) * 65536;
                    bH[(c + 2) % 3] = *(const f16x8*)(gBn);
                    bL[(c + 2) % 3] = *(const f16x8*)(gBn + 2048);
                }
                const int ss = rotl3(2 * c + h32) ^ l32;
                const f16x8 aH = ((const f16x8*)(Ahi + l32 * 256))[ss];
                const f16x8 aL = ((const f16x8*)(Alo + l32 * 256))[ss];
                // swapped operands: D[code_row][token_col]; per-code chain
                // order (H*H, L*H, H*L; chunks ascending) identical to the
                // verified kernel -> identical scores.
                acc = __builtin_amdgcn_mfma_f32_32x32x16_f16(bH[cs], aH, acc, 0, 0, 0);
                acc = __builtin_amdgcn_mfma_f32_32x32x16_f16(bL[cs], aH, acc, 0, 0, 0);
                acc = __builtin_amdgcn_mfma_f32_32x32x16_f16(bH[cs], aL, acc, 0, 0, 0);
            }

            // scores for this pass's 32 codes; fold into running best
#pragma unroll
            for (int r = 0; r < 16; ++r) {
                const int cd = wave * 128 + p * 32 + (r & 3) + 8 * (r >> 2) + 4 * h32;
                const float sc = e2Lds[cd] - 2.0f * acc[r];
                if (sc < bsv || (sc == bsv && cd < biv)) { bsv = sc; biv = cd; }
            }
        }

        // ---- merge with the other 32-lane half, write per-wave best ----
        {
            const float so = __shfl_xor(bsv, 32);
            const int   io = __shfl_xor(biv, 32);
            if (so < bsv || (so == bsv && io < biv)) { bsv = so; biv = io; }
            if (h32 == 0) {
                bestS[wave * 35 + l32] = bsv;
                bestI[wave * 35 + l32] = biv;
            }
        }
        __syncthreads();

        // ---- cross-wave argmin: 256 threads, 1 entry each + shuffle merge ----
        if (tid < 256) {
            const int t = tid >> 3;           // token 0..31
            const int g = tid & 7;            // wave index
            float bs = bestS[g * 35 + t];
            int   bi = bestI[g * 35 + t];
#pragma unroll
            for (int m = 1; m < 8; m <<= 1) {
                const float so = __shfl_xor(bs, m);
                const int   io = __shfl_xor(bi, m);
                if (so < bs || (so == bs && io < bi)) { bs = so; bi = io; }
            }
            if (g == 0) {
                indF[t] = bi;
                atomicAdd(&counts[q * KCODES + bi], 1);
            }
        }
        __syncthreads();

        // ---- update: r -= quantize (in LDS); loss partial ----
        {
            const int tl = tid >> 4;          // token 0..31
            const int sg = tid & 15;          // 16-dim strip
            const int csel = indF[tl];
            const float* gq = embedTq + csel * 256 + sg * 16;
            float lp = 0.f;
            f16x8* rowH = (f16x8*)(Ahi + tl * 256);
            f16x8* rowL = (f16x8*)(Alo + tl * 256);
#pragma unroll
            for (int it = 0; it < 2; ++it) {
                const int slot = rotl3(sg * 2 + it) ^ (tl & 31);
                f16x8 h8 = rowH[slot];
                f16x8 l8 = rowL[slot];
                const float4 q0 = *(const float4*)(gq + it * 8);
                const float4 q1 = *(const float4*)(gq + it * 8 + 4);
                const float qv[8] = {q0.x, q0.y, q0.z, q0.w, q1.x, q1.y, q1.z, q1.w};
#pragma unroll
                for (int e = 0; e < 8; ++e) {
                    const float rv = (float)h8[e] + (float)l8[e];
                    const float nr = rv - qv[e];
                    lp += nr * nr;
                    const _Float16 nh = (_Float16)nr;
                    h8[e] = nh;
                    l8[e] = (_Float16)(nr - (float)nh);
                }
                rowH[slot] = h8;
                rowL[slot] = l8;
            }
            // loss reduction: wave -> block
#pragma unroll
            for (int off = 32; off > 0; off >>= 1) lp += __shfl_down(lp, off);
            if (lane == 0) lossRed[wave] = lp;
        }
        __syncthreads();
        if (tid < 64) {
            float v = (lane < 8) ? lossRed[lane] : 0.f;
#pragma unroll
            for (int off = 4; off > 0; off >>= 1) v += __shfl_down(v, off);
            if (lane == 0) atomicAdd(lossSum + q, v);
        }
        // next iter's e2Lds/A reads are fenced by its own __syncthreads.
    }

    // ---- writeback: out = x - residual_final, coalesced ----
#pragma unroll
    for (int k = 0; k < 2; ++k) {
        const int si = tid + k * 512;
        const int t  = si >> 5;
        const int s  = si & 31;
        const int ss = rotl3(s) ^ (t & 31);
        const f16x8 h8 = ((const f16x8*)(Ahi + t * 256))[ss];
        const f16x8 l8 = ((const f16x8*)(Alo + t * 256))[ss];
        const float4 x0 = *(const float4*)(x + (tok0 + t) * 256 + s * 8);
        const float4 x1 = *(const float4*)(x + (tok0 + t) * 256 + s * 8 + 4);
        float4 o0, o1;
        o0.x = x0.x - ((float)h8[0] + (float)l8[0]);
        o0.y = x0.y - ((float)h8[1] + (float)l8[1]);
        o0.z = x0.z - ((float)h8[2] + (float)l8[2]);
        o0.w = x0.w - ((float)h8[3] + (float)l8[3]);
        o1.x = x1.x - ((float)h8[4] + (float)l8[4]);
        o1.y = x1.y - ((float)h8[5] + (float)l8[5]);
        o1.z = x1.z - ((float)h8[6] + (float)l8[6]);
        o1.w = x1.w - ((float)h8[7] + (float)l8[7]);
        *(float4*)(out + (tok0 + t) * 256 + s * 8)     = o0;
        *(float4*)(out + (tok0 + t) * 256 + s * 8 + 4) = o1;
    }
}

// ---------------------------------------------------------------------------
// Finalize: losses + perplexities into the output tail.
// ---------------------------------------------------------------------------
__global__ __launch_bounds__(256)
void vq_finalize(const int* __restrict__ counts, const float* __restrict__ lossSum,
                 float* __restrict__ outTail) {
    const int q = blockIdx.x;
    const int tid = threadIdx.x;
    float s = 0.f;
    for (int k = tid; k < KCODES; k += 256) {
        const float p = (float)counts[q * KCODES + k] * (1.0f / 65536.0f);
        s += p * logf(p + 1e-10f);
    }
    for (int off = 32; off > 0; off >>= 1) s += __shfl_down(s, off);
    __shared__ float wpart[4];
    if ((tid & 63) == 0) wpart[tid >> 6] = s;
    __syncthreads();
    if (tid == 0) {
        outTail[q]     = lossSum[q] * (1.0f / 16777216.0f);   // mean * COMMITMENT
        outTail[8 + q] = expf(-(wpart[0] + wpart[1] + wpart[2] + wpart[3]));
    }
}

// ---------------------------------------------------------------------------
extern "C" void kernel_launch(void* const* d_in, const int* in_sizes, int n_in,
                              void* d_out, int out_size, void* d_ws, size_t ws_size,
                              hipStream_t stream) {
    const float* x      = (const float*)d_in[0];   // [32,2048,256]
    const float* embeds = (const float*)d_in[1];   // [8,256,1024]
    float* out = (float*)d_out;                    // 16777216 + 8 + 8

    // Workspace layout (float units unless noted):
    float* embedT   = (float*)d_ws;                     // 2,097,152
    float* e2       = embedT + 2097152;                 // 8,192
    float* lossSum  = e2 + 8192;                        // 8
    int*   counts   = (int*)(lossSum + 8);              // 8,192
    _Float16* embedB = (_Float16*)(counts + 8192);      // 4,194,304 halfs (8 MB)

    hipMemsetAsync(lossSum, 0, (8 + 8192) * sizeof(float), stream);

    vq_transpose<<<8192, 256, 0, stream>>>(embeds, embedT);
    vq_e2<<<32, 256, 0, stream>>>(embeds, e2);
    vq_embedB<<<16384, 256, 0, stream>>>(embeds, embedB);

    hipFuncSetAttribute((const void*)vq_fused,
                        hipFuncAttributeMaxDynamicSharedMemorySize, LDS_BYTES);
    vq_fused<<<NTOK / TOKPB, 512, LDS_BYTES, stream>>>(
        x, out, embedT, e2, embedB, lossSum, counts);

    vq_finalize<<<NQ, 256, 0, stream>>>(counts, lossSum, out + NELEM);
}

// Round 7
// 1379.484 us; speedup vs baseline: 2.1311x; 2.1311x over previous
//
#include <hip/hip_runtime.h>
#include <math.h>
#include <stdint.h>

// Problem constants
#define NQ 8
#define DIMV 256
#define KCODES 1024
#define NTOK 65536              // 32*2048
#define NELEM (NTOK * DIMV)     // 16777216
#define TOKPB 64                // tokens per block in fused kernel

typedef _Float16 f16x8 __attribute__((ext_vector_type(8)));
typedef float    f32x16 __attribute__((ext_vector_type(16)));

// rotate-left-3 of a 5-bit slot index (bijective bank-spreading permutation)
__device__ __forceinline__ int rotl3(int s) { return ((s << 3) | (s >> 2)) & 31; }

// ---------------------------------------------------------------------------
// Pre-pass 1: transpose embeds [q][d][k] -> embedT [q][k][d] (fp32, for the
// quantize gather in the update phase).
// ---------------------------------------------------------------------------
__global__ __launch_bounds__(256)
void vq_transpose(const float* __restrict__ embeds, float* __restrict__ embedT) {
    const int idx = blockIdx.x * 256 + threadIdx.x;       // 0 .. 2097151
    const int q   = idx >> 18;
    const int rem = idx & 262143;
    const int k   = rem >> 8;
    const int d   = rem & 255;
    embedT[idx] = embeds[q * 262144 + d * 1024 + k];
}

// Pre-pass 2: e2[q][k] = sum_d embed[q][d][k]^2 (fp32)
__global__ __launch_bounds__(256)
void vq_e2(const float* __restrict__ embeds, float* __restrict__ e2) {
    const int idx = blockIdx.x * 256 + threadIdx.x;       // 0 .. 8191
    const int q = idx >> 10;
    const int k = idx & 1023;
    const float* e = embeds + q * 262144 + k;
    float s = 0.f;
    for (int d = 0; d < DIMV; ++d) {
        const float v = e[d * 1024];
        s += v * v;
    }
    e2[idx] = s;
}

// ---------------------------------------------------------------------------
// Pre-pass 3: split embed into fp16 hi/lo laid out as per-(layer,chunk,range)
// 4 KB images read straight into registers by the fused kernel:
//   embedB[q][chunk(16)][w(16)][part(2)][s(128)][j(8)]   (halfs)
// s = h*64 + cl ; d = chunk*16 + h*8 + j ; k = w*64 + cl
// Fragment read: lane(l32,h32), tile ct -> s = h32*64 + ct*32 + l32
// (lane-contiguous 16B slots -> one coalesced global_load_dwordx4).
// ---------------------------------------------------------------------------
__global__ __launch_bounds__(256)
void vq_embedB(const float* __restrict__ embeds, _Float16* __restrict__ embedB) {
    const int idx = blockIdx.x * 256 + threadIdx.x;       // 0 .. 4194303
    const int j    = idx & 7;
    const int s    = (idx >> 3) & 127;
    const int part = (idx >> 10) & 1;
    const int w    = (idx >> 11) & 15;
    const int c    = (idx >> 15) & 15;
    const int q    = idx >> 19;
    const int h  = s >> 6;
    const int cl = s & 63;
    const int d  = c * 16 + h * 8 + j;
    const int k  = w * 64 + cl;
    const float v = embeds[q * 262144 + d * 1024 + k];
    const _Float16 hi = (_Float16)v;
    embedB[idx] = (part == 0) ? hi : (_Float16)(v - (float)hi);
}

// ---------------------------------------------------------------------------
// Fused 8-layer VQ kernel: 1024 blocks x 1024 threads (16 waves), 64
// tokens/block (the round-4 measured-best structure, 1355 us). Residual
// lives in LDS (fp16 hi/lo) across all 8 layers.
//
// Round-7 change: __launch_bounds__(1024, 4). Without the min-waves arg the
// compiler allocated for an 8-waves/SIMD (64-reg) target -> 2 blocks/CU
// register-wise, but the HW only ever ran 1 block/CU (Occupancy 47%), so we
// paid ~250 MB of spill round-trips for nothing. Declaring 4 waves/EU gives
// the allocator the full 128 unified regs/wave that 16 waves/CU allows:
// in-loop live set (32 AGPR acc + 48 B-prefetch + 16 A-frags + misc) fits.
// ---------------------------------------------------------------------------
// LDS layout (bytes):
//  [0,     32768)  A_hi : 64 rows x 256 d fp16; 16B-block s of row t at
//                         slot rotl3(s)^(t&31)
//  [32768, 65536)  A_lo : same layout
//  [65536, 69696)  bestS  float[16][65]  (stride 65: bank-spread)
//  [69696, 73856)  bestI  int  [16][65]
//  [73856, 74112)  indF   int  [64]
//  [74112, 74176)  lossRed float[16]
//  [74176, 78272)  e2Lds  float[1024]
#define LDS_BYTES 78272

__global__ __launch_bounds__(1024, 4)
void vq_fused(const float* __restrict__ x, float* __restrict__ out,
              const float* __restrict__ embedT, const float* __restrict__ e2,
              const _Float16* __restrict__ embedB,
              float* __restrict__ lossSum, int* __restrict__ counts) {
    extern __shared__ char smem[];
    _Float16* Ahi = (_Float16*)smem;
    _Float16* Alo = (_Float16*)(smem + 32768);
    float* bestS   = (float*)(smem + 65536);
    int*   bestI   = (int*)(smem + 69696);
    int*   indF    = (int*)(smem + 73856);
    float* lossRed = (float*)(smem + 74112);
    float* e2Lds   = (float*)(smem + 74176);

    const int tid    = threadIdx.x;
    const int wave   = tid >> 6;       // 0..15
    const int lane   = tid & 63;
    const int l32    = lane & 31;
    const int h32    = lane >> 5;
    const int tok0   = blockIdx.x * TOKPB;
    const int codeBase = wave * 64;

    // ---- stage x -> A hi/lo (swizzled), ONCE for all 8 layers ----
#pragma unroll
    for (int k = 0; k < 2; ++k) {
        const int si = tid + k * 1024;         // 0..2047 (t,s) pairs
        const int t  = si >> 5;
        const int s  = si & 31;
        const float4 v0 = *(const float4*)(x + (tok0 + t) * 256 + s * 8);
        const float4 v1 = *(const float4*)(x + (tok0 + t) * 256 + s * 8 + 4);
        const float vv[8] = {v0.x, v0.y, v0.z, v0.w, v1.x, v1.y, v1.z, v1.w};
        f16x8 h8, l8;
#pragma unroll
        for (int e = 0; e < 8; ++e) {
            const _Float16 hi = (_Float16)vv[e];
            h8[e] = hi;
            l8[e] = (_Float16)(vv[e] - (float)hi);
        }
        const int ss = rotl3(s) ^ (t & 31);
        ((f16x8*)(Ahi + t * 256))[ss] = h8;
        ((f16x8*)(Alo + t * 256))[ss] = l8;
    }

    // ---- 8 residual-VQ layers, residual resident in LDS ----
#pragma unroll 1
    for (int q = 0; q < NQ; ++q) {
        const _Float16* embedBq = embedB + q * 524288;
        const float*    embedTq = embedT + q * (KCODES * DIMV);

        // stage this layer's e2 into LDS (broadcast-read in score phase)
        e2Lds[tid] = e2[q * KCODES + tid];
        // barrier covers: initial/updated A writes + e2 writes
        __syncthreads();

        const char* gBw = (const char*)embedBq + wave * 4096 + h32 * 1024 + l32 * 16;

        // running per-token best over this wave's 64 codes (kept across passes)
        float bsv0 = 3.4e38f, bsv1 = 3.4e38f;
        int   biv0 = 0x7fffffff, biv1 = 0x7fffffff;

        // ---- two 32-code passes: acc = 32 regs, depth-2 B prefetch ----
#pragma unroll
        for (int pass = 0; pass < 2; ++pass) {
            f32x16 acc[2];
#pragma unroll
            for (int tt = 0; tt < 2; ++tt)
#pragma unroll
                for (int r = 0; r < 16; ++r) acc[tt][r] = 0.f;

            const char* gBp = gBw + pass * 512;

            // 3-slot rotating prefetch buffer (all indices compile-time)
            f16x8 bH[3], bL[3];
            bH[0] = *(const f16x8*)(gBp);
            bL[0] = *(const f16x8*)(gBp + 2048);
            bH[1] = *(const f16x8*)(gBp + 65536);
            bL[1] = *(const f16x8*)(gBp + 65536 + 2048);

#pragma unroll
            for (int c = 0; c < 16; ++c) {
                const int cs = c % 3;
                if (c < 14) {
                    const char* gBn = gBp + (c + 2) * 65536;
                    bH[(c + 2) % 3] = *(const f16x8*)(gBn);
                    bL[(c + 2) % 3] = *(const f16x8*)(gBn + 2048);
                }
                f16x8 aH[2], aL[2];
#pragma unroll
                for (int tt = 0; tt < 2; ++tt) {
                    const int t  = tt * 32 + l32;
                    const int ss = rotl3(2 * c + h32) ^ l32;
                    aH[tt] = ((const f16x8*)(Ahi + t * 256))[ss];
                    aL[tt] = ((const f16x8*)(Alo + t * 256))[ss];
                }
                // swapped operands: D[code_row][token_col]; per-tile chain
                // order (H*H, L*H, H*L; chunks ascending) identical to the
                // verified kernel -> bit-identical scores.
#pragma unroll
                for (int tt = 0; tt < 2; ++tt) {
                    acc[tt] = __builtin_amdgcn_mfma_f32_32x32x16_f16(
                        bH[cs], aH[tt], acc[tt], 0, 0, 0);
                    acc[tt] = __builtin_amdgcn_mfma_f32_32x32x16_f16(
                        bL[cs], aH[tt], acc[tt], 0, 0, 0);
                    acc[tt] = __builtin_amdgcn_mfma_f32_32x32x16_f16(
                        bH[cs], aL[tt], acc[tt], 0, 0, 0);
                }
            }

            // scores for this pass's 32 codes; fold into running best
#pragma unroll
            for (int tt = 0; tt < 2; ++tt) {
                float bs = (tt == 0) ? bsv0 : bsv1;
                int   bi = (tt == 0) ? biv0 : biv1;
#pragma unroll
                for (int r = 0; r < 16; ++r) {
                    const int cd = codeBase + pass * 32 + (r & 3) + 8 * (r >> 2) + 4 * h32;
                    const float sc = e2Lds[cd] - 2.0f * acc[tt][r];
                    if (sc < bs || (sc == bs && cd < bi)) { bs = sc; bi = cd; }
                }
                if (tt == 0) { bsv0 = bs; biv0 = bi; } else { bsv1 = bs; biv1 = bi; }
            }
        }

        // ---- merge with the other 32-lane half, write per-wave best ----
#pragma unroll
        for (int tt = 0; tt < 2; ++tt) {
            float bs = (tt == 0) ? bsv0 : bsv1;
            int   bi = (tt == 0) ? biv0 : biv1;
            const float so = __shfl_xor(bs, 32);
            const int   io = __shfl_xor(bi, 32);
            if (so < bs || (so == bs && io < bi)) { bs = so; bi = io; }
            if (h32 == 0) {
                bestS[wave * 65 + tt * 32 + l32] = bs;
                bestI[wave * 65 + tt * 32 + l32] = bi;
            }
        }
        __syncthreads();

        // ---- cross-wave argmin: 256 threads, 4 waves' entries each ----
        if (tid < 256) {
            const int t = tid >> 2;           // token 0..63
            const int g = tid & 3;            // wave-group
            float bs = 3.4e38f;
            int   bi = 0x7fffffff;
#pragma unroll
            for (int i = 0; i < 4; ++i) {
                const int w = g * 4 + i;
                const float s2 = bestS[w * 65 + t];
                const int   i2 = bestI[w * 65 + t];
                if (s2 < bs || (s2 == bs && i2 < bi)) { bs = s2; bi = i2; }
            }
#pragma unroll
            for (int m = 1; m < 4; m <<= 1) {
                const float so = __shfl_xor(bs, m);
                const int   io = __shfl_xor(bi, m);
                if (so < bs || (so == bs && io < bi)) { bs = so; bi = io; }
            }
            if (g == 0) {
                indF[t] = bi;
                atomicAdd(&counts[q * KCODES + bi], 1);
            }
        }
        __syncthreads();

        // ---- update: r -= quantize (in LDS); loss partial ----
        {
            const int tl = tid >> 4;          // token 0..63
            const int sg = tid & 15;          // 16-dim strip
            const int csel = indF[tl];
            const float* gq = embedTq + csel * 256 + sg * 16;
            float lp = 0.f;
            f16x8* rowH = (f16x8*)(Ahi + tl * 256);
            f16x8* rowL = (f16x8*)(Alo + tl * 256);
#pragma unroll
            for (int it = 0; it < 2; ++it) {
                const int slot = rotl3(sg * 2 + it) ^ (tl & 31);
                f16x8 h8 = rowH[slot];
                f16x8 l8 = rowL[slot];
                const float4 q0 = *(const float4*)(gq + it * 8);
                const float4 q1 = *(const float4*)(gq + it * 8 + 4);
                const float qv[8] = {q0.x, q0.y, q0.z, q0.w, q1.x, q1.y, q1.z, q1.w};
#pragma unroll
                for (int e = 0; e < 8; ++e) {
                    const float rv = (float)h8[e] + (float)l8[e];
                    const float nr = rv - qv[e];
                    lp += nr * nr;
                    const _Float16 nh = (_Float16)nr;
                    h8[e] = nh;
                    l8[e] = (_Float16)(nr - (float)nh);
                }
                rowH[slot] = h8;
                rowL[slot] = l8;
            }
            // loss reduction: wave -> block
#pragma unroll
            for (int off = 32; off > 0; off >>= 1) lp += __shfl_down(lp, off);
            if (lane == 0) lossRed[wave] = lp;
        }
        __syncthreads();
        if (tid < 64) {
            float v = (lane < 16) ? lossRed[lane] : 0.f;
#pragma unroll
            for (int off = 8; off > 0; off >>= 1) v += __shfl_down(v, off);
            if (lane == 0) atomicAdd(lossSum + q, v);
        }
        // next iter's e2Lds/A reads are fenced by its own __syncthreads.
    }

    // ---- writeback: out = x - residual_final, coalesced ----
#pragma unroll
    for (int k = 0; k < 2; ++k) {
        const int si = tid + k * 1024;
        const int t  = si >> 5;
        const int s  = si & 31;
        const int ss = rotl3(s) ^ (t & 31);
        const f16x8 h8 = ((const f16x8*)(Ahi + t * 256))[ss];
        const f16x8 l8 = ((const f16x8*)(Alo + t * 256))[ss];
        const float4 x0 = *(const float4*)(x + (tok0 + t) * 256 + s * 8);
        const float4 x1 = *(const float4*)(x + (tok0 + t) * 256 + s * 8 + 4);
        float4 o0, o1;
        o0.x = x0.x - ((float)h8[0] + (float)l8[0]);
        o0.y = x0.y - ((float)h8[1] + (float)l8[1]);
        o0.z = x0.z - ((float)h8[2] + (float)l8[2]);
        o0.w = x0.w - ((float)h8[3] + (float)l8[3]);
        o1.x = x1.x - ((float)h8[4] + (float)l8[4]);
        o1.y = x1.y - ((float)h8[5] + (float)l8[5]);
        o1.z = x1.z - ((float)h8[6] + (float)l8[6]);
        o1.w = x1.w - ((float)h8[7] + (float)l8[7]);
        *(float4*)(out + (tok0 + t) * 256 + s * 8)     = o0;
        *(float4*)(out + (tok0 + t) * 256 + s * 8 + 4) = o1;
    }
}

// ---------------------------------------------------------------------------
// Finalize: losses + perplexities into the output tail.
// ---------------------------------------------------------------------------
__global__ __launch_bounds__(256)
void vq_finalize(const int* __restrict__ counts, const float* __restrict__ lossSum,
                 float* __restrict__ outTail) {
    const int q = blockIdx.x;
    const int tid = threadIdx.x;
    float s = 0.f;
    for (int k = tid; k < KCODES; k += 256) {
        const float p = (float)counts[q * KCODES + k] * (1.0f / 65536.0f);
        s += p * logf(p + 1e-10f);
    }
    for (int off = 32; off > 0; off >>= 1) s += __shfl_down(s, off);
    __shared__ float wpart[4];
    if ((tid & 63) == 0) wpart[tid >> 6] = s;
    __syncthreads();
    if (tid == 0) {
        outTail[q]     = lossSum[q] * (1.0f / 16777216.0f);   // mean * COMMITMENT
        outTail[8 + q] = expf(-(wpart[0] + wpart[1] + wpart[2] + wpart[3]));
    }
}

// ---------------------------------------------------------------------------
extern "C" void kernel_launch(void* const* d_in, const int* in_sizes, int n_in,
                              void* d_out, int out_size, void* d_ws, size_t ws_size,
                              hipStream_t stream) {
    const float* x      = (const float*)d_in[0];   // [32,2048,256]
    const float* embeds = (const float*)d_in[1];   // [8,256,1024]
    float* out = (float*)d_out;                    // 16777216 + 8 + 8

    // Workspace layout (float units unless noted):
    float* embedT   = (float*)d_ws;                     // 2,097,152
    float* e2       = embedT + 2097152;                 // 8,192
    float* lossSum  = e2 + 8192;                        // 8
    int*   counts   = (int*)(lossSum + 8);              // 8,192
    _Float16* embedB = (_Float16*)(counts + 8192);      // 4,194,304 halfs (8 MB)

    hipMemsetAsync(lossSum, 0, (8 + 8192) * sizeof(float), stream);

    vq_transpose<<<8192, 256, 0, stream>>>(embeds, embedT);
    vq_e2<<<32, 256, 0, stream>>>(embeds, e2);
    vq_embedB<<<16384, 256, 0, stream>>>(embeds, embedB);

    hipFuncSetAttribute((const void*)vq_fused,
                        hipFuncAttributeMaxDynamicSharedMemorySize, LDS_BYTES);
    vq_fused<<<NTOK / TOKPB, 1024, LDS_BYTES, stream>>>(
        x, out, embedT, e2, embedB, lossSum, counts);

    vq_finalize<<<NQ, 256, 0, stream>>>(counts, lossSum, out + NELEM);
}

// Round 9
// 1189.200 us; speedup vs baseline: 2.4721x; 1.1600x over previous
//
#include <hip/hip_runtime.h>
#include <math.h>
#include <stdint.h>

// Problem constants
#define NQ 8
#define DIMV 256
#define KCODES 1024
#define NTOK 65536              // 32*2048
#define NELEM (NTOK * DIMV)     // 16777216
#define TOKPB 64                // tokens per block in fused kernel

typedef _Float16 f16x8 __attribute__((ext_vector_type(8)));
typedef float    f32x16 __attribute__((ext_vector_type(16)));

// rotate-left-3 of a 5-bit slot index (bijective bank-spreading permutation)
__device__ __forceinline__ int rotl3(int s) { return ((s << 3) | (s >> 2)) & 31; }

// ---------------------------------------------------------------------------
// Pre-pass 1: transpose embeds [q][d][k] -> embedT [q][k][d] (fp32, for the
// quantize gather in the update phase).
// ---------------------------------------------------------------------------
__global__ __launch_bounds__(256)
void vq_transpose(const float* __restrict__ embeds, float* __restrict__ embedT) {
    const int idx = blockIdx.x * 256 + threadIdx.x;       // 0 .. 2097151
    const int q   = idx >> 18;
    const int rem = idx & 262143;
    const int k   = rem >> 8;
    const int d   = rem & 255;
    embedT[idx] = embeds[q * 262144 + d * 1024 + k];
}

// Pre-pass 2: e2[q][k] = sum_d embed[q][d][k]^2 (fp32)
__global__ __launch_bounds__(256)
void vq_e2(const float* __restrict__ embeds, float* __restrict__ e2) {
    const int idx = blockIdx.x * 256 + threadIdx.x;       // 0 .. 8191
    const int q = idx >> 10;
    const int k = idx & 1023;
    const float* e = embeds + q * 262144 + k;
    float s = 0.f;
    for (int d = 0; d < DIMV; ++d) {
        const float v = e[d * 1024];
        s += v * v;
    }
    e2[idx] = s;
}

// ---------------------------------------------------------------------------
// Pre-pass 3: split embed into fp16 hi/lo laid out as per-(layer,chunk,range)
// 4 KB images read straight into registers by the fused kernel:
//   embedB[q][chunk(16)][w(16)][part(2)][s(128)][j(8)]   (halfs)
// s = h*64 + cl ; d = chunk*16 + h*8 + j ; k = w*64 + cl
// Fragment read: lane(l32,h32), sub-tile ct -> s = h32*64 + ct*32 + l32
// (lane-contiguous 16B slots -> one coalesced global_load_dwordx4).
// ---------------------------------------------------------------------------
__global__ __launch_bounds__(256)
void vq_embedB(const float* __restrict__ embeds, _Float16* __restrict__ embedB) {
    const int idx = blockIdx.x * 256 + threadIdx.x;       // 0 .. 4194303
    const int j    = idx & 7;
    const int s    = (idx >> 3) & 127;
    const int part = (idx >> 10) & 1;
    const int w    = (idx >> 11) & 15;
    const int c    = (idx >> 15) & 15;
    const int q    = idx >> 19;
    const int h  = s >> 6;
    const int cl = s & 63;
    const int d  = c * 16 + h * 8 + j;
    const int k  = w * 64 + cl;
    const float v = embeds[q * 262144 + d * 1024 + k];
    const _Float16 hi = (_Float16)v;
    embedB[idx] = (part == 0) ? hi : (_Float16)(v - (float)hi);
}

// ---------------------------------------------------------------------------
// Fused 8-layer VQ kernel (round-8): 1024 blocks x 512 threads (8 waves),
// 64 tokens/block. Residual lives in LDS (fp16 hi/lo) across all 8 layers.
//
// Why 8 waves: the 16-wave (1024-thread) shape pins the CU to ONE resident
// block (2 blocks would need <=64 unified regs/wave; the hot loop needs
// ~96-128), so every per-layer barrier phase idled the whole CU (r4/r7:
// MfmaUtil 27%, occupancy 46%, 1360 us). With 8-wave blocks the SAME
// per-wave register budget (128 unified @ 4 waves/SIMD) admits TWO blocks
// per CU (LDS 2 x 72.3 KB = 145 KB < 160 KB), whose independent barrier
// domains overlap serial phases with the other block's K-loop. TOKPB stays
// 64: round-6 proved smaller token-blocks double codebook traffic and go
// HBM-bound. Each wave covers 128 codes as four 32-code passes (acc[2] =
// 32 AGPR, depth-2 B prefetch, all indices compile-time -> no spill).
// ---------------------------------------------------------------------------
// LDS layout (bytes):
//  [0,     32768)  A_hi : 64 rows x 256 d fp16; 16B-block s of row t at
//                         slot rotl3(s)^(t&31)
//  [32768, 65536)  A_lo : same layout
//  [65536, 67616)  bestS  float[8][65]  (stride 65: bank-spread)
//  [67616, 69696)  bestI  int  [8][65]
//  [69696, 69952)  indF   int  [64]
//  [69952, 69984)  lossRed float[8]
//  [69984, 74080)  e2Lds  float[1024]
#define LDS_BYTES 74080

__global__ __launch_bounds__(512, 4)
void vq_fused(const float* __restrict__ x, float* __restrict__ out,
              const float* __restrict__ embedT, const float* __restrict__ e2,
              const _Float16* __restrict__ embedB,
              float* __restrict__ lossSum, int* __restrict__ counts) {
    extern __shared__ char smem[];
    _Float16* Ahi = (_Float16*)smem;
    _Float16* Alo = (_Float16*)(smem + 32768);
    float* bestS   = (float*)(smem + 65536);
    int*   bestI   = (int*)(smem + 67616);
    int*   indF    = (int*)(smem + 69696);
    float* lossRed = (float*)(smem + 69952);
    float* e2Lds   = (float*)(smem + 69984);

    const int tid    = threadIdx.x;
    const int wave   = tid >> 6;       // 0..7
    const int lane   = tid & 63;
    const int l32    = lane & 31;
    const int h32    = lane >> 5;
    const int tok0   = blockIdx.x * TOKPB;

    // ---- stage x -> A hi/lo (swizzled), ONCE for all 8 layers ----
#pragma unroll
    for (int k = 0; k < 4; ++k) {
        const int si = tid + k * 512;          // 0..2047 (t,s) pairs
        const int t  = si >> 5;
        const int s  = si & 31;
        const float4 v0 = *(const float4*)(x + (tok0 + t) * 256 + s * 8);
        const float4 v1 = *(const float4*)(x + (tok0 + t) * 256 + s * 8 + 4);
        const float vv[8] = {v0.x, v0.y, v0.z, v0.w, v1.x, v1.y, v1.z, v1.w};
        f16x8 h8, l8;
#pragma unroll
        for (int e = 0; e < 8; ++e) {
            const _Float16 hi = (_Float16)vv[e];
            h8[e] = hi;
            l8[e] = (_Float16)(vv[e] - (float)hi);
        }
        const int ss = rotl3(s) ^ (t & 31);
        ((f16x8*)(Ahi + t * 256))[ss] = h8;
        ((f16x8*)(Alo + t * 256))[ss] = l8;
    }

    // ---- 8 residual-VQ layers, residual resident in LDS ----
#pragma unroll 1
    for (int q = 0; q < NQ; ++q) {
        const _Float16* embedBq = embedB + q * 524288;
        const float*    embedTq = embedT + q * (KCODES * DIMV);

        // stage this layer's e2 into LDS (broadcast-read in score phase)
        e2Lds[tid]       = e2[q * KCODES + tid];
        e2Lds[tid + 512] = e2[q * KCODES + tid + 512];
        // barrier covers: initial/updated A writes + e2 writes
        __syncthreads();

        // running per-token best over this wave's 128 codes
        float bsv0 = 3.4e38f, bsv1 = 3.4e38f;
        int   biv0 = 0x7fffffff, biv1 = 0x7fffffff;

        // ---- four 32-code passes: acc[2] = 32 AGPR, depth-2 B prefetch ----
#pragma unroll
        for (int p = 0; p < 4; ++p) {
            f32x16 acc[2];
#pragma unroll
            for (int tt = 0; tt < 2; ++tt)
#pragma unroll
                for (int r = 0; r < 16; ++r) acc[tt][r] = 0.f;

            // image (2*wave + p>>1) covers codes [wave*128+(p>>1)*64, +64);
            // (p&1) selects the 32-code half (ct offset 512 B).
            const char* gBp = (const char*)embedBq + (2 * wave + (p >> 1)) * 4096
                              + (p & 1) * 512 + h32 * 1024 + l32 * 16;

            // 3-slot rotating prefetch buffer (all indices compile-time)
            f16x8 bH[3], bL[3];
            bH[0] = *(const f16x8*)(gBp);
            bL[0] = *(const f16x8*)(gBp + 2048);
            bH[1] = *(const f16x8*)(gBp + 65536);
            bL[1] = *(const f16x8*)(gBp + 65536 + 2048);

#pragma unroll
            for (int c = 0; c < 16; ++c) {
                const int cs = c % 3;
                if (c < 14) {
                    const char* gBn = gBp + (c + 2) * 65536;
                    bH[(c + 2) % 3] = *(const f16x8*)(gBn);
                    bL[(c + 2) % 3] = *(const f16x8*)(gBn + 2048);
                }
                f16x8 aH[2], aL[2];
#pragma unroll
                for (int tt = 0; tt < 2; ++tt) {
                    const int t  = tt * 32 + l32;
                    const int ss = rotl3(2 * c + h32) ^ l32;
                    aH[tt] = ((const f16x8*)(Ahi + t * 256))[ss];
                    aL[tt] = ((const f16x8*)(Alo + t * 256))[ss];
                }
                // swapped operands: D[code_row][token_col]; per-tile chain
                // order (H*H, L*H, H*L; chunks ascending) identical to the
                // verified kernel -> bit-identical scores.
#pragma unroll
                for (int tt = 0; tt < 2; ++tt) {
                    acc[tt] = __builtin_amdgcn_mfma_f32_32x32x16_f16(
                        bH[cs], aH[tt], acc[tt], 0, 0, 0);
                    acc[tt] = __builtin_amdgcn_mfma_f32_32x32x16_f16(
                        bL[cs], aH[tt], acc[tt], 0, 0, 0);
                    acc[tt] = __builtin_amdgcn_mfma_f32_32x32x16_f16(
                        bH[cs], aL[tt], acc[tt], 0, 0, 0);
                }
            }

            // scores for this pass's 32 codes; fold into running best
#pragma unroll
            for (int tt = 0; tt < 2; ++tt) {
                float bs = (tt == 0) ? bsv0 : bsv1;
                int   bi = (tt == 0) ? biv0 : biv1;
#pragma unroll
                for (int r = 0; r < 16; ++r) {
                    const int cd = wave * 128 + p * 32 + (r & 3) + 8 * (r >> 2) + 4 * h32;
                    const float sc = e2Lds[cd] - 2.0f * acc[tt][r];
                    if (sc < bs || (sc == bs && cd < bi)) { bs = sc; bi = cd; }
                }
                if (tt == 0) { bsv0 = bs; biv0 = bi; } else { bsv1 = bs; biv1 = bi; }
            }
        }

        // ---- merge with the other 32-lane half, write per-wave best ----
#pragma unroll
        for (int tt = 0; tt < 2; ++tt) {
            float bs = (tt == 0) ? bsv0 : bsv1;
            int   bi = (tt == 0) ? biv0 : biv1;
            const float so = __shfl_xor(bs, 32);
            const int   io = __shfl_xor(bi, 32);
            if (so < bs || (so == bs && io < bi)) { bs = so; bi = io; }
            if (h32 == 0) {
                bestS[wave * 65 + tt * 32 + l32] = bs;
                bestI[wave * 65 + tt * 32 + l32] = bi;
            }
        }
        __syncthreads();

        // ---- cross-wave argmin: all 512 threads, shuffle merge over 8 ----
        {
            const int t = tid >> 3;           // token 0..63
            const int g = tid & 7;            // wave index
            float bs = bestS[g * 65 + t];
            int   bi = bestI[g * 65 + t];
#pragma unroll
            for (int m = 1; m < 8; m <<= 1) {
                const float so = __shfl_xor(bs, m);
                const int   io = __shfl_xor(bi, m);
                if (so < bs || (so == bs && io < bi)) { bs = so; bi = io; }
            }
            if (g == 0) {
                indF[t] = bi;
                atomicAdd(&counts[q * KCODES + bi], 1);
            }
        }
        __syncthreads();

        // ---- update: r -= quantize (in LDS); loss partial ----
        {
            const int tl = tid >> 3;          // token 0..63
            const int sg = tid & 7;           // 32-dim strip (4 slots)
            const int csel = indF[tl];
            const float* gq = embedTq + csel * 256;
            float lp = 0.f;
            f16x8* rowH = (f16x8*)(Ahi + tl * 256);
            f16x8* rowL = (f16x8*)(Alo + tl * 256);
#pragma unroll
            for (int it = 0; it < 4; ++it) {
                const int slotIdx = sg * 4 + it;          // 0..31
                const int slot = rotl3(slotIdx) ^ (tl & 31);
                f16x8 h8 = rowH[slot];
                f16x8 l8 = rowL[slot];
                const float4 q0 = *(const float4*)(gq + slotIdx * 8);
                const float4 q1 = *(const float4*)(gq + slotIdx * 8 + 4);
                const float qv[8] = {q0.x, q0.y, q0.z, q0.w, q1.x, q1.y, q1.z, q1.w};
#pragma unroll
                for (int e = 0; e < 8; ++e) {
                    const float rv = (float)h8[e] + (float)l8[e];
                    const float nr = rv - qv[e];
                    lp += nr * nr;
                    const _Float16 nh = (_Float16)nr;
                    h8[e] = nh;
                    l8[e] = (_Float16)(nr - (float)nh);
                }
                rowH[slot] = h8;
                rowL[slot] = l8;
            }
            // loss reduction: wave -> block
#pragma unroll
            for (int off = 32; off > 0; off >>= 1) lp += __shfl_down(lp, off);
            if (lane == 0) lossRed[wave] = lp;
        }
        __syncthreads();
        if (tid < 64) {
            float v = (lane < 8) ? lossRed[lane] : 0.f;
#pragma unroll
            for (int off = 4; off > 0; off >>= 1) v += __shfl_down(v, off);
            if (lane == 0) atomicAdd(lossSum + q, v);
        }
        // next iter's e2Lds/A reads are fenced by its own __syncthreads.
    }

    // ---- writeback: out = x - residual_final, coalesced ----
#pragma unroll
    for (int k = 0; k < 4; ++k) {
        const int si = tid + k * 512;
        const int t  = si >> 5;
        const int s  = si & 31;
        const int ss = rotl3(s) ^ (t & 31);
        const f16x8 h8 = ((const f16x8*)(Ahi + t * 256))[ss];
        const f16x8 l8 = ((const f16x8*)(Alo + t * 256))[ss];
        const float4 x0 = *(const float4*)(x + (tok0 + t) * 256 + s * 8);
        const float4 x1 = *(const float4*)(x + (tok0 + t) * 256 + s * 8 + 4);
        float4 o0, o1;
        o0.x = x0.x - ((float)h8[0] + (float)l8[0]);
        o0.y = x0.y - ((float)h8[1] + (float)l8[1]);
        o0.z = x0.z - ((float)h8[2] + (float)l8[2]);
        o0.w = x0.w - ((float)h8[3] + (float)l8[3]);
        o1.x = x1.x - ((float)h8[4] + (float)l8[4]);
        o1.y = x1.y - ((float)h8[5] + (float)l8[5]);
        o1.z = x1.z - ((float)h8[6] + (float)l8[6]);
        o1.w = x1.w - ((float)h8[7] + (float)l8[7]);
        *(float4*)(out + (tok0 + t) * 256 + s * 8)     = o0;
        *(float4*)(out + (tok0 + t) * 256 + s * 8 + 4) = o1;
    }
}

// ---------------------------------------------------------------------------
// Finalize: losses + perplexities into the output tail.
// ---------------------------------------------------------------------------
__global__ __launch_bounds__(256)
void vq_finalize(const int* __restrict__ counts, const float* __restrict__ lossSum,
                 float* __restrict__ outTail) {
    const int q = blockIdx.x;
    const int tid = threadIdx.x;
    float s = 0.f;
    for (int k = tid; k < KCODES; k += 256) {
        const float p = (float)counts[q * KCODES + k] * (1.0f / 65536.0f);
        s += p * logf(p + 1e-10f);
    }
    for (int off = 32; off > 0; off >>= 1) s += __shfl_down(s, off);
    __shared__ float wpart[4];
    if ((tid & 63) == 0) wpart[tid >> 6] = s;
    __syncthreads();
    if (tid == 0) {
        outTail[q]     = lossSum[q] * (1.0f / 16777216.0f);   // mean * COMMITMENT
        outTail[8 + q] = expf(-(wpart[0] + wpart[1] + wpart[2] + wpart[3]));
    }
}

// ---------------------------------------------------------------------------
extern "C" void kernel_launch(void* const* d_in, const int* in_sizes, int n_in,
                              void* d_out, int out_size, void* d_ws, size_t ws_size,
                              hipStream_t stream) {
    const float* x      = (const float*)d_in[0];   // [32,2048,256]
    const float* embeds = (const float*)d_in[1];   // [8,256,1024]
    float* out = (float*)d_out;                    // 16777216 + 8 + 8

    // Workspace layout (float units unless noted):
    float* embedT   = (float*)d_ws;                     // 2,097,152
    float* e2       = embedT + 2097152;                 // 8,192
    float* lossSum  = e2 + 8192;                        // 8
    int*   counts   = (int*)(lossSum + 8);              // 8,192
    _Float16* embedB = (_Float16*)(counts + 8192);      // 4,194,304 halfs (8 MB)

    hipMemsetAsync(lossSum, 0, (8 + 8192) * sizeof(float), stream);

    vq_transpose<<<8192, 256, 0, stream>>>(embeds, embedT);
    vq_e2<<<32, 256, 0, stream>>>(embeds, e2);
    vq_embedB<<<16384, 256, 0, stream>>>(embeds, embedB);

    hipFuncSetAttribute((const void*)vq_fused,
                        hipFuncAttributeMaxDynamicSharedMemorySize, LDS_BYTES);
    vq_fused<<<NTOK / TOKPB, 512, LDS_BYTES, stream>>>(
        x, out, embedT, e2, embedB, lossSum, counts);

    vq_finalize<<<NQ, 256, 0, stream>>>(counts, lossSum, out + NELEM);
}